// Round 3
// baseline (88.733 us; speedup 1.0000x reference)
//
#include <hip/hip_runtime.h>
#include <math.h>

#define N 768
#define CS 384
#define CP 128
#define NBIN 65
#define MT 128   // m-tile per pair-kernel block

typedef float f4 __attribute__((ext_vector_type(4)));

// Fused kernel 1: blocks [0, N/2) do the two projections (2 rows each);
// blocks [N/2, ...) build relT[bin][p] = W_rel[p][bin] + b_rel[p] + b_t[p].
__global__ __launch_bounds__(256) void prep_kernel(
    const float* __restrict__ s,
    const float* __restrict__ Wi, const float* __restrict__ bi,
    const float* __restrict__ Wj, const float* __restrict__ bj,
    const float* __restrict__ Wrel, const float* __restrict__ brel,
    const float* __restrict__ bt,
    float* __restrict__ pI, float* __restrict__ pJ, float* __restrict__ relT) {
  const int tid = threadIdx.x;

  if (blockIdx.x >= N / 2) {
    const int bb = (blockIdx.x - N / 2) * 2 + (tid >> 7);
    const int p = tid & 127;
    if (bb < NBIN)
      relT[bb * CP + p] = Wrel[p * NBIN + bb] + brel[p] + bt[p];
    return;
  }

  __shared__ float s_sh[2 * CS];
  const int n0 = blockIdx.x * 2;
  if (tid < 2 * CS / 4)
    reinterpret_cast<f4*>(s_sh)[tid] = reinterpret_cast<const f4*>(s + n0 * CS)[tid];
  __syncthreads();

  const int which = tid >> 7;   // 0 -> i projection, 1 -> j projection
  const int p = tid & 127;
  const float* W = which ? Wj : Wi;
  const float b = which ? bj[p] : bi[p];
  const f4* W4 = reinterpret_cast<const f4*>(W + p * CS);
  const f4* S4 = reinterpret_cast<const f4*>(s_sh);

  float acc0 = b, acc1 = b;
#pragma unroll 8
  for (int c4 = 0; c4 < CS / 4; ++c4) {
    const f4 w = W4[c4];
    const f4 s0 = S4[c4];
    const f4 s1 = S4[CS / 4 + c4];
    acc0 += s0.x * w.x + s0.y * w.y + s0.z * w.z + s0.w * w.w;
    acc1 += s1.x * w.x + s1.y * w.y + s1.z * w.z + s1.w * w.w;
  }
  float* outp = which ? pJ : pI;
  outp[(n0 + 0) * CP + p] = acc0;
  outp[(n0 + 1) * CP + p] = acc1;
}

// Kernel 2: out[n][m][p] = (pI[n][p] + pJ[m][p] + relT[bin(n-m)][p] + dist(n,m)*W_t[p]) * mask[n][m]
// Block = (n, 128-m tile). 256 threads = 8 slots x 32 float4-lanes.
// Fast path: tile entirely off the |n-m|<32 band -> rel is block-uniform,
// folded into a per-thread register base (1 load per 16B store).
__global__ __launch_bounds__(256) void pair_kernel(
    const float* __restrict__ pI, const float* __restrict__ pJ,
    const float* __restrict__ relT, const float* __restrict__ Wt,
    const float* __restrict__ trans, const float* __restrict__ mask,
    float* __restrict__ out) {
  __shared__ float dist_sh[MT];
  __shared__ float msk_sh[MT];

  const int n = blockIdx.y;
  const int m0 = blockIdx.x * MT;
  const int tid = threadIdx.x;

  if (tid < MT) {
    const int m = m0 + tid;
    const float dx = trans[n * 3 + 0] - trans[m * 3 + 0];
    const float dy = trans[n * 3 + 1] - trans[m * 3 + 1];
    const float dz = trans[n * 3 + 2] - trans[m * 3 + 2];
    dist_sh[tid] = sqrtf(1e-10f + dx * dx + dy * dy + dz * dz);
    msk_sh[tid] = mask[n * N + m];
  }
  __syncthreads();

  const int v = tid & 31;        // float4 index within 128 channels
  const int slot = tid >> 5;     // 0..7

  const f4 wt4 = reinterpret_cast<const f4*>(Wt)[v];
  const f4 pi4 = reinterpret_cast<const f4*>(pI)[n * (CP / 4) + v];
  const f4* __restrict__ pJ4 = reinterpret_cast<const f4*>(pJ);
  const f4* __restrict__ rel4 = reinterpret_cast<const f4*>(relT);
  f4* __restrict__ out4 = reinterpret_cast<f4*>(out) + ((size_t)n * N + m0) * (CP / 4);

  const int dmax = n - m0;              // d over tile: [dmax-(MT-1), dmax]
  const int dmin = dmax - (MT - 1);

  if (dmin >= 32 || dmax <= -32) {
    // rel bin uniform over the whole tile
    const int bin = (dmin >= 32) ? 64 : 0;
    const f4 base = pi4 + rel4[bin * (CP / 4) + v];
#pragma unroll 8
    for (int k = 0; k < MT / 8; ++k) {
      const int mi = k * 8 + slot;
      const f4 pj4 = pJ4[(m0 + mi) * (CP / 4) + v];
      const float dist = dist_sh[mi];
      const float msk = msk_sh[mi];
      f4 o = (base + pj4 + dist * wt4) * msk;
      __builtin_nontemporal_store(o, &out4[mi * (CP / 4) + v]);
    }
  } else {
#pragma unroll 8
    for (int k = 0; k < MT / 8; ++k) {
      const int mi = k * 8 + slot;
      const int m = m0 + mi;
      int d = n - m;
      d = d < -32 ? -32 : (d > 32 ? 32 : d);
      const f4 pj4 = pJ4[m * (CP / 4) + v];
      const f4 rl = rel4[(d + 32) * (CP / 4) + v];
      const float dist = dist_sh[mi];
      const float msk = msk_sh[mi];
      f4 o = (pi4 + pj4 + rl + dist * wt4) * msk;
      __builtin_nontemporal_store(o, &out4[mi * (CP / 4) + v]);
    }
  }
}

extern "C" void kernel_launch(void* const* d_in, const int* in_sizes, int n_in,
                              void* d_out, int out_size, void* d_ws, size_t ws_size,
                              hipStream_t stream) {
  const float* s      = (const float*)d_in[0];
  const float* trans  = (const float*)d_in[1];
  const float* p_mask = (const float*)d_in[2];
  const float* Wi     = (const float*)d_in[3];
  const float* bi     = (const float*)d_in[4];
  const float* Wj     = (const float*)d_in[5];
  const float* bj     = (const float*)d_in[6];
  const float* Wrel   = (const float*)d_in[7];
  const float* brel   = (const float*)d_in[8];
  const float* Wt     = (const float*)d_in[9];
  const float* bt     = (const float*)d_in[10];
  float* out = (float*)d_out;

  float* ws   = (float*)d_ws;
  float* pI   = ws;                 // N*CP floats
  float* pJ   = ws + N * CP;        // N*CP floats
  float* relT = ws + 2 * N * CP;    // NBIN*CP floats

  prep_kernel<<<N / 2 + (NBIN + 1) / 2, 256, 0, stream>>>(
      s, Wi, bi, Wj, bj, Wrel, brel, bt, pI, pJ, relT);
  pair_kernel<<<dim3(N / MT, N), 256, 0, stream>>>(
      pI, pJ, relT, Wt, trans, p_mask, out);
}

// Round 4
// 73.428 us; speedup vs baseline: 1.2084x; 1.2084x over previous
//
#include <hip/hip_runtime.h>
#include <math.h>

#define N 768
#define CS 384
#define CP 128
#define NBIN 65
#define MT 64   // m-tile per pair-kernel block

typedef float f4 __attribute__((ext_vector_type(4)));
typedef float f2 __attribute__((ext_vector_type(2)));

// Fused kernel 1: blocks [0, N/4) do the two projections (4 rows each);
// blocks [N/4, ...) build relT[bin][p] = W_rel[p][bin] + b_rel[p] + b_t[p].
__global__ __launch_bounds__(256) void prep_kernel(
    const float* __restrict__ s,
    const float* __restrict__ Wi, const float* __restrict__ bi,
    const float* __restrict__ Wj, const float* __restrict__ bj,
    const float* __restrict__ Wrel, const float* __restrict__ brel,
    const float* __restrict__ bt,
    float* __restrict__ pI, float* __restrict__ pJ, float* __restrict__ relT) {
  const int tid = threadIdx.x;

  if (blockIdx.x >= N / 4) {
    const int bb = (blockIdx.x - N / 4) * 2 + (tid >> 7);
    const int p = tid & 127;
    if (bb < NBIN)
      relT[bb * CP + p] = Wrel[p * NBIN + bb] + brel[p] + bt[p];
    return;
  }

  __shared__ float s_sh[4 * CS];
  const int n0 = blockIdx.x * 4;
  for (int i = tid; i < 4 * CS / 4; i += 256)
    reinterpret_cast<f4*>(s_sh)[i] = reinterpret_cast<const f4*>(s + n0 * CS)[i];
  __syncthreads();

  const int which = tid >> 7;   // 0 -> i projection, 1 -> j projection
  const int p = tid & 127;
  const float* W = which ? Wj : Wi;
  const float b = which ? bj[p] : bi[p];
  const f4* W4 = reinterpret_cast<const f4*>(W + p * CS);
  const f4* S4 = reinterpret_cast<const f4*>(s_sh);

  float acc0 = b, acc1 = b, acc2 = b, acc3 = b;
  for (int c4 = 0; c4 < CS / 4; ++c4) {
    const f4 w = W4[c4];
    const f4 s0 = S4[0 * (CS / 4) + c4];
    const f4 s1 = S4[1 * (CS / 4) + c4];
    const f4 s2 = S4[2 * (CS / 4) + c4];
    const f4 s3 = S4[3 * (CS / 4) + c4];
    acc0 += s0.x * w.x + s0.y * w.y + s0.z * w.z + s0.w * w.w;
    acc1 += s1.x * w.x + s1.y * w.y + s1.z * w.z + s1.w * w.w;
    acc2 += s2.x * w.x + s2.y * w.y + s2.z * w.z + s2.w * w.w;
    acc3 += s3.x * w.x + s3.y * w.y + s3.z * w.z + s3.w * w.w;
  }
  float* outp = which ? pJ : pI;
  outp[(n0 + 0) * CP + p] = acc0;
  outp[(n0 + 1) * CP + p] = acc1;
  outp[(n0 + 2) * CP + p] = acc2;
  outp[(n0 + 3) * CP + p] = acc3;
}

// Kernel 2: out[n][m][p] = (pI[n][p] + pJ[m][p] + relT[bin(n-m)][p] + dist(n,m)*W_t[p]) * mask[n][m]
// Block = (n, 64-m tile). 256 threads = 8 slots x 32 float4-lanes.
// Plain (cached) stores: the 7 TB/s fill kernel uses plain stores; nt bypass was the
// suspected store-path throttle in R2.
__global__ __launch_bounds__(256) void pair_kernel(
    const float* __restrict__ pI, const float* __restrict__ pJ,
    const float* __restrict__ relT, const float* __restrict__ Wt,
    const float* __restrict__ trans, const float* __restrict__ mask,
    float* __restrict__ out) {
  __shared__ f2 dm_sh[MT];   // {dist, mask} per m

  const int n = blockIdx.y;
  const int m0 = blockIdx.x * MT;
  const int tid = threadIdx.x;

  if (tid < MT) {
    const int m = m0 + tid;
    const float dx = trans[n * 3 + 0] - trans[m * 3 + 0];
    const float dy = trans[n * 3 + 1] - trans[m * 3 + 1];
    const float dz = trans[n * 3 + 2] - trans[m * 3 + 2];
    f2 dm;
    dm.x = sqrtf(1e-10f + dx * dx + dy * dy + dz * dz);
    dm.y = mask[n * N + m];
    dm_sh[tid] = dm;
  }
  __syncthreads();

  const int v = tid & 31;        // float4 index within 128 channels
  const int slot = tid >> 5;     // 0..7

  const f4 pi4 = reinterpret_cast<const f4*>(pI)[n * (CP / 4) + v];
  const f4 wt4 = reinterpret_cast<const f4*>(Wt)[v];
  const f4* __restrict__ pJ4 = reinterpret_cast<const f4*>(pJ);
  const f4* __restrict__ rel4 = reinterpret_cast<const f4*>(relT);
  f4* __restrict__ out4 = reinterpret_cast<f4*>(out) + ((size_t)n * N + m0) * (CP / 4);

#pragma unroll
  for (int k = 0; k < MT / 8; ++k) {
    const int mi = k * 8 + slot;         // wave's 2 slots -> adjacent m -> 1KB contiguous store
    const int m = m0 + mi;
    int d = n - m;
    d = d < -32 ? -32 : (d > 32 ? 32 : d);

    const f4 pj4 = pJ4[m * (CP / 4) + v];
    const f4 rl = rel4[(d + 32) * (CP / 4) + v];
    const f2 dm = dm_sh[mi];

    f4 o;
    o.x = (pi4.x + pj4.x + rl.x + dm.x * wt4.x) * dm.y;
    o.y = (pi4.y + pj4.y + rl.y + dm.x * wt4.y) * dm.y;
    o.z = (pi4.z + pj4.z + rl.z + dm.x * wt4.z) * dm.y;
    o.w = (pi4.w + pj4.w + rl.w + dm.x * wt4.w) * dm.y;

    out4[mi * (CP / 4) + v] = o;
  }
}

extern "C" void kernel_launch(void* const* d_in, const int* in_sizes, int n_in,
                              void* d_out, int out_size, void* d_ws, size_t ws_size,
                              hipStream_t stream) {
  const float* s      = (const float*)d_in[0];
  const float* trans  = (const float*)d_in[1];
  const float* p_mask = (const float*)d_in[2];
  const float* Wi     = (const float*)d_in[3];
  const float* bi     = (const float*)d_in[4];
  const float* Wj     = (const float*)d_in[5];
  const float* bj     = (const float*)d_in[6];
  const float* Wrel   = (const float*)d_in[7];
  const float* brel   = (const float*)d_in[8];
  const float* Wt     = (const float*)d_in[9];
  const float* bt     = (const float*)d_in[10];
  float* out = (float*)d_out;

  float* ws   = (float*)d_ws;
  float* pI   = ws;                 // N*CP floats
  float* pJ   = ws + N * CP;        // N*CP floats
  float* relT = ws + 2 * N * CP;    // NBIN*CP floats

  prep_kernel<<<N / 4 + (NBIN + 1) / 2, 256, 0, stream>>>(
      s, Wi, bi, Wj, bj, Wrel, brel, bt, pI, pJ, relT);
  pair_kernel<<<dim3(N / MT, N), 256, 0, stream>>>(
      pI, pJ, relT, Wt, trans, p_mask, out);
}